// Round 16
// baseline (134.309 us; speedup 1.0000x reference)
//
#include <hip/hip_runtime.h>
#include <hip/hip_bf16.h>

typedef unsigned short u16;
typedef __attribute__((ext_vector_type(8))) short bf16x8;
typedef __attribute__((ext_vector_type(4))) float f32x4;
typedef __attribute__((ext_vector_type(4))) unsigned short u16x4;
typedef __attribute__((ext_vector_type(8))) unsigned short u16x8v;

#define SQ 4096
#define HQ 128
#define NCHUNK 144   // per batch: sum over qt2 of ceil((qt2+1)/4), chunk = 8 key-tiles

__device__ __forceinline__ u16 f2b(float f) {
  unsigned int u = __float_as_uint(f);
  unsigned int r = (u + 0x7fffu + ((u >> 16) & 1u)) >> 16;  // RNE bf16
  return (u16)r;
}

__device__ __forceinline__ u16 f2b_fast(float f) {
  __hip_bfloat16 h = __float2bfloat16(f);
  return __builtin_bit_cast(u16, h);
}

__device__ __forceinline__ float b2f(u16 v) {
  unsigned int u = ((unsigned int)v) << 16;
  return __uint_as_float(u);
}

__device__ __forceinline__ void gload_lds16(const void* gsrc, void* ldst) {
  __builtin_amdgcn_global_load_lds((const __attribute__((address_space(1))) void*)gsrc,
                                   (__attribute__((address_space(3))) void*)ldst, 16, 0, 0);
}

// prep: x f32 -> bf16 (blocks 0..8191) and Wt[z][n][k] = W_z[k][n] (blocks 8192+)
__global__ __launch_bounds__(256) void k_prep(const float* __restrict__ x,
                                              const float* __restrict__ Wq, const float* __restrict__ Wk,
                                              const float* __restrict__ Wv,
                                              u16* __restrict__ xb, u16* __restrict__ wt) {
  int bid = blockIdx.x;
  if (bid < 8192) {
    long i = ((long)bid * 256 + threadIdx.x) * 8;
    float4 a = *(const float4*)(x + i);
    float4 c = *(const float4*)(x + i + 4);
    u16x8v o;
    o[0] = f2b(a.x); o[1] = f2b(a.y); o[2] = f2b(a.z); o[3] = f2b(a.w);
    o[4] = f2b(c.x); o[5] = f2b(c.y); o[6] = f2b(c.z); o[7] = f2b(c.w);
    *(u16x8v*)(xb + i) = o;
  } else {
    int idx = (bid - 8192) * 256 + threadIdx.x;
    int z = idx >> 17, r = idx & 131071, n = r >> 10, k = r & 1023;
    const float* W = (z == 0) ? Wq : (z == 1) ? Wk : Wv;
    wt[idx] = f2b(W[k * 128 + n]);
  }
}

// proj v9 = m97 replica: tile 128x128, grid (128,3), 256 thr (4 waves 2x2,
// wave 64x64, acc[4][4]). Per wave/iter: 4+4 ds_read_b128 + 16 MFMA. A (xb
// bf16) and B (wt bf16) both staged via global_load_lds w16 (pre-swizzled
// source, chunk^((row>>1)&3), 2-way = free), double-buffered, 1 barrier/iter.
__global__ __launch_bounds__(256, 4) void k_proj(const u16* __restrict__ xb, const u16* __restrict__ wt,
                                                 u16* __restrict__ qb, u16* __restrict__ kb,
                                                 u16* __restrict__ vt) {
  int mt = blockIdx.x, nh = blockIdx.y;
  int t = threadIdx.x;
  int w = t >> 6, lane = t & 63;
  int wm = w >> 1, wn = w & 1;
  int lr = lane & 15, lg = lane >> 4;

  __shared__ __align__(16) u16 Al[2][128 * 32];   // 2 x 8 KB
  __shared__ __align__(16) u16 Bl[2][128 * 32];   // 2 x 8 KB

  f32x4 acc[4][4];
#pragma unroll
  for (int i = 0; i < 4; ++i)
#pragma unroll
    for (int j = 0; j < 4; ++j) acc[i][j] = (f32x4){0.f, 0.f, 0.f, 0.f};

  const u16* xbase = xb + (long)(mt * 128) * 1024;
  const u16* wbase = wt + (long)(nh * 128) * 1024;

  // stage: A 512 chunks + B 512 chunks (128 rows x 4 chunks each), 2+2/thread
  auto stage = [&](int bufi, int k0) {
#pragma unroll
    for (int i = 0; i < 2; ++i) {
      int ci = i * 256 + t;
      int row = ci >> 2, ch = ci & 3;
      gload_lds16(xbase + (long)row * 1024 + k0 + ((ch ^ ((row >> 1) & 3)) << 3),
                  &Al[bufi][0] + ci * 8);
    }
#pragma unroll
    for (int i = 0; i < 2; ++i) {
      int ci = i * 256 + t;
      int row = ci >> 2, ch = ci & 3;
      gload_lds16(wbase + (long)row * 1024 + k0 + ((ch ^ ((row >> 1) & 3)) << 3),
                  &Bl[bufi][0] + ci * 8);
    }
  };

  stage(0, 0);
  __syncthreads();

  for (int ks = 0; ks < 32; ++ks) {
    int cur = ks & 1;
    if (ks + 1 < 32) stage(cur ^ 1, (ks + 1) * 32);   // async prefetch
    bf16x8 af[4], bfr[4];
#pragma unroll
    for (int i = 0; i < 4; ++i) {
      int row = wm * 64 + i * 16 + lr;
      af[i] = *(const bf16x8*)(&Al[cur][0] + row * 32 + ((lg ^ ((row >> 1) & 3)) << 3));
    }
#pragma unroll
    for (int j = 0; j < 4; ++j) {
      int row = wn * 64 + j * 16 + lr;
      bfr[j] = *(const bf16x8*)(&Bl[cur][0] + row * 32 + ((lg ^ ((row >> 1) & 3)) << 3));
    }
#pragma unroll
    for (int i = 0; i < 4; ++i)
#pragma unroll
      for (int j = 0; j < 4; ++j)
        acc[i][j] = __builtin_amdgcn_mfma_f32_16x16x32_bf16(af[i], bfr[j], acc[i][j], 0, 0, 0);
    __syncthreads();
  }

  // epilogue: C layout row=(lane>>4)*4+reg, col=lane&15; nh = head (0:Q 1:K 2:V)
#pragma unroll
  for (int i = 0; i < 4; ++i)
#pragma unroll
    for (int j = 0; j < 4; ++j)
#pragma unroll
      for (int r = 0; r < 4; ++r) {
        int m = mt * 128 + wm * 64 + i * 16 + lg * 4 + r;
        int cz = wn * 64 + j * 16 + lr;
        u16 v = f2b(acc[i][j][r]);
        if (nh == 0) qb[(long)m * 128 + cz] = v;
        else if (nh == 1) kb[(long)m * 128 + cz] = v;
        else { int bb = m >> 12, sR = m & 4095; vt[(long)bb * 524288 + (long)cz * 4096 + sR] = v; }
      }
}

// flash attention v6 (proven ~54us): uniform split-K chunks (8 key-tiles);
// 576 blocks. 8-wave blocks share K/V staging, QBLK=128, KVBLK=64,
// double-buffered, fixed-max softmax, ones-MFMA row-sum, bf16 partials.
__global__ __launch_bounds__(512, 4) void k_attn(const u16* __restrict__ qb, const u16* __restrict__ kb,
                                                 const u16* __restrict__ vt, const int* __restrict__ kmask,
                                                 u16* __restrict__ po, float* __restrict__ pl) {
  const float SCALE_LOG2 = 0.08838834764831845f * 1.4426950408889634f;
  const float MFIX = 24.0f;
  int f = (NCHUNK - 1) - (int)blockIdx.x;  // long chunks (big qt2) first
  int b = blockIdx.y;
  int qt2 = 0, cum = 0;
  while (cum + ((qt2 + 4) >> 2) <= f) { cum += (qt2 + 4) >> 2; ++qt2; }
  int kc = f - cum;
  int ntile = 2 * qt2 + 2;
  int kt0 = kc * 8;
  int kt1 = min(kt0 + 8, ntile);

  int t = threadIdx.x, w = t >> 6, lane = t & 63;
  int lr = lane & 15, lg = lane >> 4, sw = lr & 7;
  int qrow0 = qt2 * 128 + w * 16;
  const u16* Q = qb + ((long)(b * SQ + qrow0)) * HQ;
  const u16* K = kb + (long)b * SQ * HQ;
  const u16* V = vt + (long)b * HQ * SQ;   // V^T: [128][SQ]
  const int* msk = kmask + b * SQ;

  __shared__ __align__(16) u16 Kl[2][64 * 128];   // 2 x 16 KB
  __shared__ __align__(16) u16 Vl[2][128 * 64];   // 2 x 16 KB
  __shared__ __align__(16) u16 plds[8][16 * 64];  // 16 KB, XOR-chunk layout

  bf16x8 aq[4];
#pragma unroll
  for (int c = 0; c < 4; ++c) aq[c] = *(const bf16x8*)(Q + lr * HQ + c * 32 + lg * 8);

  bf16x8 ones;
#pragma unroll
  for (int e = 0; e < 8; ++e) ones[e] = (short)0x3F80;

  f32x4 o[8];
#pragma unroll
  for (int n = 0; n < 8; ++n) o[n] = (f32x4){0.f, 0.f, 0.f, 0.f};
  f32x4 l_acc = (f32x4){0.f, 0.f, 0.f, 0.f};

  auto stage = [&](int bufi, int kb0) {
    const u16* Kg = K + (long)kb0 * HQ;
    const u16* Vg = V + kb0;
#pragma unroll
    for (int i = 0; i < 2; ++i) {
      int ci = w * 2 + i;
      int o16 = ci * 64 + lane;
      int row = o16 >> 4, ch = o16 & 15;
      gload_lds16(Kg + row * HQ + ((ch ^ (row & 7)) << 3), &Kl[bufi][ci * 512]);
    }
#pragma unroll
    for (int i = 0; i < 2; ++i) {
      int ci = w * 2 + i;
      int o16 = ci * 64 + lane;
      int row = o16 >> 3, ch = o16 & 7;
      gload_lds16(Vg + (long)row * SQ + ((ch ^ (row & 7)) << 3), &Vl[bufi][ci * 512]);
    }
  };

  stage(0, kt0 * 64);
  __syncthreads();

  u16* pw = &plds[w][0];
  for (int kt = kt0; kt < kt1; ++kt) {
    int cur = (kt - kt0) & 1;
    int kb0 = kt * 64;
    if (kt + 1 < kt1) stage(cur ^ 1, kb0 + 64);

    if (kb0 <= qrow0 + 15) {                 // wave-uniform: any valid keys?
      f32x4 s[4];
#pragma unroll
      for (int h = 0; h < 4; ++h) {
        f32x4 acc = (f32x4){0.f, 0.f, 0.f, 0.f};
        const u16* Kp = &Kl[cur][(h * 16 + lr) * 128];
#pragma unroll
        for (int c = 0; c < 4; ++c) {
          bf16x8 bk = *(const bf16x8*)(Kp + (((c * 4 + lg) ^ sw) << 3));
          acc = __builtin_amdgcn_mfma_f32_16x16x32_bf16(aq[c], bk, acc, 0, 0, 0);
        }
        s[h] = acc;
      }
      float mf[4];
#pragma unroll
      for (int h = 0; h < 4; ++h) mf[h] = (msk[kb0 + h * 16 + lr] != 0) ? 1.0f : 0.0f;
      bool needc = (kb0 + 63 > qrow0);       // tile crosses diagonal for this wave
#pragma unroll
      for (int r = 0; r < 4; ++r) {
        int row = lg * 4 + r;
        int qr = qrow0 + row;
#pragma unroll
        for (int h = 0; h < 4; ++h) {
          float p = __builtin_exp2f(fmaf(s[h][r], SCALE_LOG2, -MFIX)) * mf[h];
          if (needc) p = ((kb0 + h * 16 + lr) <= qr) ? p : 0.0f;
          int poff = row * 64 + ((((h * 2 + (lr >> 3)) ^ (row & 7))) << 3) + (lr & 7);
          pw[poff] = f2b_fast(p);
        }
      }
      bf16x8 ap0 = *(const bf16x8*)(pw + lr * 64 + ((lg ^ sw) << 3));
      bf16x8 ap1 = *(const bf16x8*)(pw + lr * 64 + (((4 + lg) ^ sw) << 3));
      l_acc = __builtin_amdgcn_mfma_f32_16x16x32_bf16(ap0, ones, l_acc, 0, 0, 0);
      l_acc = __builtin_amdgcn_mfma_f32_16x16x32_bf16(ap1, ones, l_acc, 0, 0, 0);
#pragma unroll
      for (int n = 0; n < 8; ++n) {
        const u16* Vp = &Vl[cur][(n * 16 + lr) * 64];
        bf16x8 bv0 = *(const bf16x8*)(Vp + ((lg ^ sw) << 3));
        bf16x8 bv1 = *(const bf16x8*)(Vp + (((4 + lg) ^ sw) << 3));
        o[n] = __builtin_amdgcn_mfma_f32_16x16x32_bf16(ap0, bv0, o[n], 0, 0, 0);
        o[n] = __builtin_amdgcn_mfma_f32_16x16x32_bf16(ap1, bv1, o[n], 0, 0, 0);
      }
    }
    __syncthreads();
  }

  long p = (long)b * NCHUNK + f;
  u16* pob = po + p * 16384;  // [128][128] bf16
#pragma unroll
  for (int n = 0; n < 8; ++n)
#pragma unroll
    for (int r = 0; r < 4; ++r)
      pob[(w * 16 + lg * 4 + r) * 128 + n * 16 + lr] = f2b_fast(o[n][r]);
  if (lr == 0) {
#pragma unroll
    for (int r = 0; r < 4; ++r) pl[p * 128 + w * 16 + lg * 4 + r] = l_acc[r];
  }
}

// merge: out[b, qt2*128+row, :] = sum_i po[i] / sum_i pl[i]
__global__ __launch_bounds__(256) void k_merge(const u16* __restrict__ po, const float* __restrict__ pl,
                                               float* __restrict__ out) {
  int qt2 = blockIdx.x, b = blockIdx.y;
  int nch = (qt2 + 4) >> 2;
  int pre = 0;
  for (int q = 0; q < qt2; ++q) pre += (q + 4) >> 2;
  long pbase = (long)b * NCHUNK + pre;
  int t = threadIdx.x;
  int row = t >> 1, c0 = (t & 1) * 64;
  float l = 0.f;
  for (int i = 0; i < nch; ++i) l += pl[(pbase + i) * 128 + row];
  float inv = 1.0f / l;
  const u16* p0 = po + pbase * 16384 + row * 128 + c0;
  float* orow = out + ((long)(b * SQ + qt2 * 128 + row)) * HQ + c0;
#pragma unroll
  for (int j = 0; j < 64; j += 4) {
    float acc0 = 0.f, acc1 = 0.f, acc2 = 0.f, acc3 = 0.f;
    for (int i = 0; i < nch; ++i) {
      u16x4 v = *(const u16x4*)(p0 + (long)i * 16384 + j);
      acc0 += b2f(v[0]); acc1 += b2f(v[1]); acc2 += b2f(v[2]); acc3 += b2f(v[3]);
    }
    float4 r = {acc0 * inv, acc1 * inv, acc2 * inv, acc3 * inv};
    *(float4*)(orow + j) = r;
  }
}

extern "C" void kernel_launch(void* const* d_in, const int* in_sizes, int n_in,
                              void* d_out, int out_size, void* d_ws, size_t ws_size,
                              hipStream_t stream) {
  const float* x  = (const float*)d_in[0];
  const float* Wq = (const float*)d_in[1];
  const float* Wk = (const float*)d_in[2];
  const float* Wv = (const float*)d_in[3];
  const int* kmask = (const int*)d_in[4];
  char* ws = (char*)d_ws;
  u16* xb = (u16*)ws;                         // 32 MB: x bf16 (dead after k_proj)
  u16* wt = (u16*)(ws + 33554432);            // 768 KB: Wt (dead after k_proj)
  u16* qb = (u16*)(ws + 34340864);            // 4 MB: Q bf16
  u16* kb = (u16*)(ws + 38535168);            // 4 MB: K bf16
  u16* vt = (u16*)(ws + 42729472);            // 4 MB: V^T bf16 [4][128][4096]
  u16* po = (u16*)ws;                         // 18.9 MB partial O (reuses xb region, after proj)
  float* pl = (float*)(ws + 31195136);        // 295 KB partial l (xb-region tail, after proj)
  float* out = (float*)d_out;

  k_prep<<<9728, 256, 0, stream>>>(x, Wq, Wk, Wv, xb, wt);
  k_proj<<<dim3(128, 3), 256, 0, stream>>>(xb, wt, qb, kb, vt);
  k_attn<<<dim3(NCHUNK, 4), 512, 0, stream>>>(qb, kb, vt, kmask, po, pl);
  k_merge<<<dim3(32, 4), 256, 0, stream>>>(po, pl, out);
}